// Round 8
// baseline (665.096 us; speedup 1.0000x reference)
//
#include <hip/hip_runtime.h>

// ---------------------------------------------------------------------------
// GCN variational encoder (mu, logvar) on MI355X — round 8.
//   h[n] = dinv[n] * ( xs[n] + sum_{s->n} xs[s] ),  xs = bf16(dinv*x)
//   mu = h@Wmu + bmu ; logvar = h@Wlv + blv   (MFMA, bf16 W^T)
// R8: node-exact CSR sort (k_sort, 87us, 83MB scatter writes) replaced by
// 256-node BUCKETS: multisplit with per-block LDS counts + one reservation
// atomic per (block,bucket) (1.2M -> ~50k global atomics, clustered writes),
// then one block per bucket aggregates edges into a 64KB LDS f32 accumulator
// via ds_add_f32 (no global atomics, no CSR). Bucket sizes derived from deg.
// hb (bf16 h) stays TILED inside each block's own lv output slice.
// ---------------------------------------------------------------------------

typedef unsigned short u16;
typedef __attribute__((ext_vector_type(8))) short short8;   // 8 bf16 (4 VGPR)
typedef __attribute__((ext_vector_type(4))) float f32x4;

__device__ inline u16 f2bf(float f) {
    union { float f; unsigned u; } c; c.f = f;
    unsigned u = c.u;
    return (u16)((u + 0x7FFFu + ((u >> 16) & 1u)) >> 16);  // RNE
}
__device__ inline float bf2f(u16 h) {
    union { unsigned u; float f; } c; c.u = ((unsigned)h) << 16;
    return c.f;
}

__global__ void k_zero(int* __restrict__ p, int n) {
    int i = blockIdx.x * blockDim.x + threadIdx.x;
    if (i < n) p[i] = 0;
}

__global__ void k_deg(const int* __restrict__ dst, int e, int* __restrict__ deg) {
    int i = blockIdx.x * blockDim.x + threadIdx.x;
    if (i < e) atomicAdd(&deg[dst[i]], 1);
}

__global__ void k_dinv(const int* __restrict__ deg, float* __restrict__ dinv, int n) {
    int i = blockIdx.x * blockDim.x + threadIdx.x;
    if (i < n) dinv[i] = rsqrtf((float)(deg[i] + 1));  // +1 = self loop
}

// xs = bf16(dinv[row] * x)
__global__ void k_xs(const float4* __restrict__ x4, const float* __restrict__ dinv,
                     ushort4* __restrict__ xs4, int n16) {
    int i = blockIdx.x * blockDim.x + threadIdx.x;
    if (i < n16) {
        float s = dinv[i >> 4];
        float4 v = x4[i];
        ushort4 o;
        o.x = f2bf(v.x * s); o.y = f2bf(v.y * s);
        o.z = f2bf(v.z * s); o.w = f2bf(v.w * s);
        xs4[i] = o;
    }
}

// WbT[mat][n][k] = bf16(W_mat[k][n])
__global__ void k_wbt(const float* __restrict__ Wmu, const float* __restrict__ Wlv,
                      u16* __restrict__ WbT) {
    int t = blockIdx.x * blockDim.x + threadIdx.x;
    if (t < 8192) {
        int mat = t >> 12;
        int n = (t >> 6) & 63;
        int k = t & 63;
        const float* W = mat ? Wlv : Wmu;
        WbT[t] = f2bf(W[k * 64 + n]);
    }
}

// bucket edge-count = sum of deg over the bucket's 256 nodes
__global__ __launch_bounds__(256) void k_bktsum(const int* __restrict__ deg,
                                                int* __restrict__ bcount, int n) {
    __shared__ int sm[256];
    const int node = (blockIdx.x << 8) + threadIdx.x;
    sm[threadIdx.x] = (node < n) ? deg[node] : 0;
    __syncthreads();
    for (int off = 128; off > 0; off >>= 1) {
        if (threadIdx.x < off) sm[threadIdx.x] += sm[threadIdx.x + off];
        __syncthreads();
    }
    if (threadIdx.x == 0) bcount[blockIdx.x] = sm[0];
}

// exclusive scan of bcount (nb <= 512) -> bstart, gtail
__global__ void k_bktscan(const int* __restrict__ bcount, int* __restrict__ bstart,
                          int* __restrict__ gtail, int nb) {
    __shared__ int sm[512];
    const int tid = threadIdx.x;
    int v = (tid < nb) ? bcount[tid] : 0;
    sm[tid] = v;
    __syncthreads();
    for (int off = 1; off < 512; off <<= 1) {
        int t = (tid >= off) ? sm[tid - off] : 0;
        __syncthreads();
        sm[tid] += t;
        __syncthreads();
    }
    if (tid < nb) { int s = sm[tid] - v; bstart[tid] = s; gtail[tid] = s; }
}

// --- multisplit: scatter edges into bucket regions -------------------------
// Phase 1: LDS histogram of this block's chunk. Phase 2: one global atomic
// per non-empty (block,bucket) reserves a range. Phase 3: re-read chunk,
// place packed (src | dstLow<<17) via LDS-cursor offsets -> writes cluster
// ~24-consecutive per bucket region.
__global__ __launch_bounds__(256) void k_split(
        const int* __restrict__ src, const int* __restrict__ dst, int e,
        int* __restrict__ gtail, unsigned* __restrict__ edgeBuf) {
    __shared__ unsigned cnt[512];
    __shared__ unsigned base[512];
    const int tid = threadIdx.x;
    const int chunk = (e + gridDim.x - 1) / gridDim.x;
    const int e0 = blockIdx.x * chunk;
    const int e1 = min(e, e0 + chunk);

    for (int b = tid; b < 512; b += 256) cnt[b] = 0;
    __syncthreads();
    for (int i = e0 + tid; i < e1; i += 256)
        atomicAdd(&cnt[(unsigned)dst[i] >> 8], 1u);
    __syncthreads();
    for (int b = tid; b < 512; b += 256) {
        unsigned c = cnt[b];
        base[b] = c ? (unsigned)atomicAdd(&gtail[b], (int)c) : 0u;
        cnt[b] = 0;
    }
    __syncthreads();
    for (int i = e0 + tid; i < e1; i += 256) {
        const int d = dst[i];
        const int b = (unsigned)d >> 8;
        const unsigned p = base[b] + atomicAdd(&cnt[b], 1u);
        edgeBuf[p] = (unsigned)src[i] | ((unsigned)(d & 255) << 17);
    }
}

// --- bucket aggregation: one block per 256-node bucket ---------------------
// 64KB LDS f32 accumulator. 16 waves; each wave takes 64 edges (one per
// lane), then broadcasts each edge via __shfl: the 64 lanes load the 128B
// bf16 xs row coalesced and ds_add_f32 into the dst row (2 lanes/bank =
// conflict-free). Epilogue: + self loop, * dinv[dst], write bf16 h TILED
// (tile = node>>6) inside the block's own lv slice region.
__global__ __launch_bounds__(1024) void k_aggb(
        const u16* __restrict__ xs, const float* __restrict__ dinv,
        const int* __restrict__ bstart, const int* __restrict__ bcount,
        const unsigned* __restrict__ edgeBuf, u16* __restrict__ hb, int n) {
    __shared__ float acc[256 * 64];                 // 64 KB
    const int tid  = threadIdx.x;
    const int lane = tid & 63;
    const int w    = tid >> 6;                      // wave 0..15
    const int node0 = blockIdx.x << 8;

    float4* a4 = (float4*)acc;
    for (int i = tid; i < 256 * 16; i += 1024)
        a4[i] = make_float4(0.f, 0.f, 0.f, 0.f);
    __syncthreads();

    const int e0 = bstart[blockIdx.x];
    const int e1 = e0 + bcount[blockIdx.x];
    for (int base = e0 + (w << 6); base < e1; base += (16 << 6)) {
        const int cnt = min(64, e1 - base);
        unsigned pk = (base + lane < e1) ? edgeBuf[base + lane] : 0u;
        if (cnt == 64) {
            #pragma unroll 8
            for (int it = 0; it < 64; ++it) {
                const unsigned p = __shfl(pk, it);
                const int s  = p & 0x1FFFF;
                const int dl = p >> 17;
                const float f = bf2f(xs[((size_t)s << 6) + lane]);
                atomicAdd(&acc[(dl << 6) + lane], f);
            }
        } else {
            for (int it = 0; it < cnt; ++it) {
                const unsigned p = __shfl(pk, it);
                const int s  = p & 0x1FFFF;
                const int dl = p >> 17;
                const float f = bf2f(xs[((size_t)s << 6) + lane]);
                atomicAdd(&acc[(dl << 6) + lane], f);
            }
        }
    }
    __syncthreads();

    for (int i = tid; i < 256 * 64; i += 1024) {
        const int r = i >> 6, c = i & 63;
        const int node = node0 + r;
        if (node < n) {
            float f = acc[i] + bf2f(xs[((size_t)node << 6) + c]);  // self loop
            f *= dinv[node];
            hb[(size_t)(node >> 6) * 8192 + (size_t)(node & 63) * 64 + c] = f2bf(f);
        }
    }
}

// --- MFMA dual GEMM (unchanged from R7) ------------------------------------
__global__ __launch_bounds__(256) void k_gemm2(
        const u16* __restrict__ hb, const u16* __restrict__ WbT,
        const float* __restrict__ bmu, const float* __restrict__ blv,
        float* __restrict__ mu, float* __restrict__ lv, int n) {
    const int tid  = threadIdx.x;
    const int lane = tid & 63;
    const int w    = tid >> 6;          // wave 0..3
    const int row0 = blockIdx.x * 64;
    const int m    = lane & 15;
    const int kg   = lane >> 4;         // 0..3

    const u16* hrow = hb + (size_t)blockIdx.x * 8192 + (size_t)(w * 16 + m) * 64 + kg * 8;
    short8 aF0 = *(const short8*)(hrow);
    short8 aF1 = *(const short8*)(hrow + 32);

    short8 bF[2][4][2];
    #pragma unroll
    for (int mat = 0; mat < 2; ++mat)
        #pragma unroll
        for (int ct = 0; ct < 4; ++ct)
            #pragma unroll
            for (int kh = 0; kh < 2; ++kh)
                bF[mat][ct][kh] = *(const short8*)(
                    WbT + mat * 4096 + (ct * 16 + m) * 64 + kh * 32 + kg * 8);

    __syncthreads();   // drain hb reads before any wave's lv stores

    #pragma unroll
    for (int mat = 0; mat < 2; ++mat) {
        const float* __restrict__ bias = mat ? blv : bmu;
        float* __restrict__ outp       = mat ? lv  : mu;
        #pragma unroll
        for (int ct = 0; ct < 4; ++ct) {
            const float bj = bias[ct * 16 + m];
            f32x4 acc = {bj, bj, bj, bj};
            acc = __builtin_amdgcn_mfma_f32_16x16x32_bf16(aF0, bF[mat][ct][0], acc, 0, 0, 0);
            acc = __builtin_amdgcn_mfma_f32_16x16x32_bf16(aF1, bF[mat][ct][1], acc, 0, 0, 0);
            #pragma unroll
            for (int i = 0; i < 4; ++i) {
                const int row = row0 + w * 16 + kg * 4 + i;
                if (row < n) outp[(size_t)row * 64 + ct * 16 + m] = acc[i];
            }
        }
    }
}

extern "C" void kernel_launch(void* const* d_in, const int* in_sizes, int n_in,
                              void* d_out, int out_size, void* d_ws, size_t ws_size,
                              hipStream_t stream) {
    const float* x   = (const float*)d_in[0];
    const int* eidx  = (const int*)d_in[1];
    const float* Wmu = (const float*)d_in[2];
    const float* bmu = (const float*)d_in[3];
    const float* Wlv = (const float*)d_in[4];
    const float* blv = (const float*)d_in[5];

    const int N = in_sizes[0] / 64;
    const int E = in_sizes[1] / 2;
    const int* src = eidx;
    const int* dst = eidx + E;
    const int NB = (N + 255) >> 8;        // 391 buckets of 256 nodes (<=512)

    // ws: deg dinv bcount bstart gtail WbT xs(bf16) edgeBuf  (~18.4 MB)
    char* ws = (char*)d_ws;
    size_t off = 0;
    int*   deg    = (int*)(ws + off);    off += ((size_t)N * 4 + 255) & ~(size_t)255;
    float* dinv   = (float*)(ws + off);  off += ((size_t)N * 4 + 255) & ~(size_t)255;
    int*   bcount = (int*)(ws + off);    off += 512 * 4;
    int*   bstart = (int*)(ws + off);    off += 512 * 4;
    int*   gtail  = (int*)(ws + off);    off += 512 * 4;
    u16*   WbT    = (u16*)(ws + off);    off += 8192 * 2;
    u16*   xsb    = (u16*)(ws + off);    off += ((size_t)N * 64 * 2 + 255) & ~(size_t)255;
    unsigned* edgeBuf = (unsigned*)(ws + off); off += ((size_t)E * 4 + 255) & ~(size_t)255;

    float* mu = (float*)d_out;
    float* lv = mu + (size_t)N * 64;
    u16*   hb = (u16*)lv;                  // bf16 h, TILED inside lv slices

    const int B = 256;

    k_zero<<<(N + B - 1) / B, B, 0, stream>>>(deg, N);
    k_deg<<<(E + B - 1) / B, B, 0, stream>>>(dst, E, deg);
    k_dinv<<<(N + B - 1) / B, B, 0, stream>>>(deg, dinv, N);
    k_wbt<<<32, 256, 0, stream>>>(Wmu, Wlv, WbT);

    k_xs<<<(N * 16 + B - 1) / B, B, 0, stream>>>((const float4*)x, dinv, (ushort4*)xsb, N * 16);

    k_bktsum<<<NB, 256, 0, stream>>>(deg, bcount, N);
    k_bktscan<<<1, 512, 0, stream>>>(bcount, bstart, gtail, NB);
    k_split<<<128, 256, 0, stream>>>(src, dst, E, gtail, edgeBuf);

    k_aggb<<<NB, 1024, 0, stream>>>(xsb, dinv, bstart, bcount, edgeBuf, hb, N);

    k_gemm2<<<(N + 63) / 64, 256, 0, stream>>>(hb, WbT, bmu, blv, mu, lv, N);
}

// Round 9
// 638.972 us; speedup vs baseline: 1.0409x; 1.0409x over previous
//
#include <hip/hip_runtime.h>

// ---------------------------------------------------------------------------
// GCN variational encoder (mu, logvar) on MI355X — round 9.
//   h[n] = dinv[n] * ( xs[n] + sum_{s->n} xs[s] ),  xs = bf16(dinv*x)
//   mu = h@Wmu + bmu ; logvar = h@Wlv + blv   (MFMA, bf16 W^T)
// R9 fix: R8's k_aggb used __shfl (ds_bpermute) to broadcast edges -> shares
// lgkmcnt with the ds_add atomics -> every edge serialized on a full
// shfl+gather+atomic latency chain (538us, VGPR=8). Now each wave reads its
// 8 edge words via wave-uniform direct indexing (scalar/broadcast loads),
// issues 8 independent 128B row gathers, then 8 ds_add_f32 -> 8-deep MLP,
// lgkm drain once per batch instead of per edge.
// ---------------------------------------------------------------------------

typedef unsigned short u16;
typedef __attribute__((ext_vector_type(8))) short short8;   // 8 bf16 (4 VGPR)
typedef __attribute__((ext_vector_type(4))) float f32x4;

__device__ inline u16 f2bf(float f) {
    union { float f; unsigned u; } c; c.f = f;
    unsigned u = c.u;
    return (u16)((u + 0x7FFFu + ((u >> 16) & 1u)) >> 16);  // RNE
}
__device__ inline float bf2f(u16 h) {
    union { unsigned u; float f; } c; c.u = ((unsigned)h) << 16;
    return c.f;
}

__global__ void k_zero(int* __restrict__ p, int n) {
    int i = blockIdx.x * blockDim.x + threadIdx.x;
    if (i < n) p[i] = 0;
}

__global__ void k_deg(const int* __restrict__ dst, int e, int* __restrict__ deg) {
    int i = blockIdx.x * blockDim.x + threadIdx.x;
    if (i < e) atomicAdd(&deg[dst[i]], 1);
}

__global__ void k_dinv(const int* __restrict__ deg, float* __restrict__ dinv, int n) {
    int i = blockIdx.x * blockDim.x + threadIdx.x;
    if (i < n) dinv[i] = rsqrtf((float)(deg[i] + 1));  // +1 = self loop
}

// xs = bf16(dinv[row] * x)
__global__ void k_xs(const float4* __restrict__ x4, const float* __restrict__ dinv,
                     ushort4* __restrict__ xs4, int n16) {
    int i = blockIdx.x * blockDim.x + threadIdx.x;
    if (i < n16) {
        float s = dinv[i >> 4];
        float4 v = x4[i];
        ushort4 o;
        o.x = f2bf(v.x * s); o.y = f2bf(v.y * s);
        o.z = f2bf(v.z * s); o.w = f2bf(v.w * s);
        xs4[i] = o;
    }
}

// WbT[mat][n][k] = bf16(W_mat[k][n])
__global__ void k_wbt(const float* __restrict__ Wmu, const float* __restrict__ Wlv,
                      u16* __restrict__ WbT) {
    int t = blockIdx.x * blockDim.x + threadIdx.x;
    if (t < 8192) {
        int mat = t >> 12;
        int n = (t >> 6) & 63;
        int k = t & 63;
        const float* W = mat ? Wlv : Wmu;
        WbT[t] = f2bf(W[k * 64 + n]);
    }
}

// bucket edge-count = sum of deg over the bucket's 256 nodes
__global__ __launch_bounds__(256) void k_bktsum(const int* __restrict__ deg,
                                                int* __restrict__ bcount, int n) {
    __shared__ int sm[256];
    const int node = (blockIdx.x << 8) + threadIdx.x;
    sm[threadIdx.x] = (node < n) ? deg[node] : 0;
    __syncthreads();
    for (int off = 128; off > 0; off >>= 1) {
        if (threadIdx.x < off) sm[threadIdx.x] += sm[threadIdx.x + off];
        __syncthreads();
    }
    if (threadIdx.x == 0) bcount[blockIdx.x] = sm[0];
}

// exclusive scan of bcount (nb <= 512) -> bstart, gtail
__global__ void k_bktscan(const int* __restrict__ bcount, int* __restrict__ bstart,
                          int* __restrict__ gtail, int nb) {
    __shared__ int sm[512];
    const int tid = threadIdx.x;
    int v = (tid < nb) ? bcount[tid] : 0;
    sm[tid] = v;
    __syncthreads();
    for (int off = 1; off < 512; off <<= 1) {
        int t = (tid >= off) ? sm[tid - off] : 0;
        __syncthreads();
        sm[tid] += t;
        __syncthreads();
    }
    if (tid < nb) { int s = sm[tid] - v; bstart[tid] = s; gtail[tid] = s; }
}

// --- multisplit: scatter edges into bucket regions -------------------------
__global__ __launch_bounds__(256) void k_split(
        const int* __restrict__ src, const int* __restrict__ dst, int e,
        int* __restrict__ gtail, unsigned* __restrict__ edgeBuf) {
    __shared__ unsigned cnt[512];
    __shared__ unsigned base[512];
    const int tid = threadIdx.x;
    const int chunk = (e + gridDim.x - 1) / gridDim.x;
    const int e0 = blockIdx.x * chunk;
    const int e1 = min(e, e0 + chunk);

    for (int b = tid; b < 512; b += 256) cnt[b] = 0;
    __syncthreads();
    for (int i = e0 + tid; i < e1; i += 256)
        atomicAdd(&cnt[(unsigned)dst[i] >> 8], 1u);
    __syncthreads();
    for (int b = tid; b < 512; b += 256) {
        unsigned c = cnt[b];
        base[b] = c ? (unsigned)atomicAdd(&gtail[b], (int)c) : 0u;
        cnt[b] = 0;
    }
    __syncthreads();
    for (int i = e0 + tid; i < e1; i += 256) {
        const int d = dst[i];
        const int b = (unsigned)d >> 8;
        const unsigned p = base[b] + atomicAdd(&cnt[b], 1u);
        edgeBuf[p] = (unsigned)src[i] | ((unsigned)(d & 255) << 17);
    }
}

// --- bucket aggregation: one block per 256-node bucket ---------------------
// 64KB LDS f32 accumulator, 16 waves. Wave w takes 8-edge batches: edge
// words fetched by WAVE-UNIFORM indexing (scalar/broadcast loads, no shfl /
// bpermute -> no lgkm entanglement with the ds atomics), then 8 independent
// 128B xs-row gathers (2B/lane), then 8 ds_add_f32 (lane-consecutive ->
// 2 lanes/bank, conflict-free). Epilogue: + self loop, * dinv, bf16 h TILED.
__global__ __launch_bounds__(1024) void k_aggb(
        const u16* __restrict__ xs, const float* __restrict__ dinv,
        const int* __restrict__ bstart, const int* __restrict__ bcount,
        const unsigned* __restrict__ edgeBuf, u16* __restrict__ hb, int n) {
    __shared__ float acc[256 * 64];                 // 64 KB
    const int tid  = threadIdx.x;
    const int lane = tid & 63;
    const int w    = tid >> 6;                      // wave 0..15
    const int node0 = blockIdx.x << 8;

    float4* a4 = (float4*)acc;
    for (int i = tid; i < 256 * 16; i += 1024)
        a4[i] = make_float4(0.f, 0.f, 0.f, 0.f);
    __syncthreads();

#define ROW(p) bf2f(xs[((size_t)((p) & 0x1FFFF) << 6) + lane])
#define ADDE(p, v) atomicAdd(&acc[(((p) >> 17) << 6) + lane], (v))

    const int e0 = bstart[blockIdx.x];
    const int e1 = e0 + bcount[blockIdx.x];
    for (int base = e0 + (w << 3); base < e1; base += 128) {   // 16 waves x 8
        if (base + 8 <= e1) {
            const unsigned p0 = edgeBuf[base + 0], p1 = edgeBuf[base + 1];
            const unsigned p2 = edgeBuf[base + 2], p3 = edgeBuf[base + 3];
            const unsigned p4 = edgeBuf[base + 4], p5 = edgeBuf[base + 5];
            const unsigned p6 = edgeBuf[base + 6], p7 = edgeBuf[base + 7];
            const float v0 = ROW(p0), v1 = ROW(p1), v2 = ROW(p2), v3 = ROW(p3);
            const float v4 = ROW(p4), v5 = ROW(p5), v6 = ROW(p6), v7 = ROW(p7);
            ADDE(p0, v0); ADDE(p1, v1); ADDE(p2, v2); ADDE(p3, v3);
            ADDE(p4, v4); ADDE(p5, v5); ADDE(p6, v6); ADDE(p7, v7);
        } else {
            for (int i = base; i < e1; ++i) {
                const unsigned p = edgeBuf[i];
                const float v = ROW(p);
                ADDE(p, v);
            }
        }
    }
#undef ROW
#undef ADDE
    __syncthreads();

    for (int i = tid; i < 256 * 64; i += 1024) {
        const int r = i >> 6, c = i & 63;
        const int node = node0 + r;
        if (node < n) {
            float f = acc[i] + bf2f(xs[((size_t)node << 6) + c]);  // self loop
            f *= dinv[node];
            hb[(size_t)(node >> 6) * 8192 + (size_t)(node & 63) * 64 + c] = f2bf(f);
        }
    }
}

// --- MFMA dual GEMM (unchanged from R7) ------------------------------------
__global__ __launch_bounds__(256) void k_gemm2(
        const u16* __restrict__ hb, const u16* __restrict__ WbT,
        const float* __restrict__ bmu, const float* __restrict__ blv,
        float* __restrict__ mu, float* __restrict__ lv, int n) {
    const int tid  = threadIdx.x;
    const int lane = tid & 63;
    const int w    = tid >> 6;          // wave 0..3
    const int row0 = blockIdx.x * 64;
    const int m    = lane & 15;
    const int kg   = lane >> 4;         // 0..3

    const u16* hrow = hb + (size_t)blockIdx.x * 8192 + (size_t)(w * 16 + m) * 64 + kg * 8;
    short8 aF0 = *(const short8*)(hrow);
    short8 aF1 = *(const short8*)(hrow + 32);

    short8 bF[2][4][2];
    #pragma unroll
    for (int mat = 0; mat < 2; ++mat)
        #pragma unroll
        for (int ct = 0; ct < 4; ++ct)
            #pragma unroll
            for (int kh = 0; kh < 2; ++kh)
                bF[mat][ct][kh] = *(const short8*)(
                    WbT + mat * 4096 + (ct * 16 + m) * 64 + kh * 32 + kg * 8);

    __syncthreads();   // drain hb reads before any wave's lv stores

    #pragma unroll
    for (int mat = 0; mat < 2; ++mat) {
        const float* __restrict__ bias = mat ? blv : bmu;
        float* __restrict__ outp       = mat ? lv  : mu;
        #pragma unroll
        for (int ct = 0; ct < 4; ++ct) {
            const float bj = bias[ct * 16 + m];
            f32x4 acc = {bj, bj, bj, bj};
            acc = __builtin_amdgcn_mfma_f32_16x16x32_bf16(aF0, bF[mat][ct][0], acc, 0, 0, 0);
            acc = __builtin_amdgcn_mfma_f32_16x16x32_bf16(aF1, bF[mat][ct][1], acc, 0, 0, 0);
            #pragma unroll
            for (int i = 0; i < 4; ++i) {
                const int row = row0 + w * 16 + kg * 4 + i;
                if (row < n) outp[(size_t)row * 64 + ct * 16 + m] = acc[i];
            }
        }
    }
}

extern "C" void kernel_launch(void* const* d_in, const int* in_sizes, int n_in,
                              void* d_out, int out_size, void* d_ws, size_t ws_size,
                              hipStream_t stream) {
    const float* x   = (const float*)d_in[0];
    const int* eidx  = (const int*)d_in[1];
    const float* Wmu = (const float*)d_in[2];
    const float* bmu = (const float*)d_in[3];
    const float* Wlv = (const float*)d_in[4];
    const float* blv = (const float*)d_in[5];

    const int N = in_sizes[0] / 64;
    const int E = in_sizes[1] / 2;
    const int* src = eidx;
    const int* dst = eidx + E;
    const int NB = (N + 255) >> 8;        // 391 buckets of 256 nodes (<=512)

    // ws: deg dinv bcount bstart gtail WbT xs(bf16) edgeBuf  (~18.4 MB)
    char* ws = (char*)d_ws;
    size_t off = 0;
    int*   deg    = (int*)(ws + off);    off += ((size_t)N * 4 + 255) & ~(size_t)255;
    float* dinv   = (float*)(ws + off);  off += ((size_t)N * 4 + 255) & ~(size_t)255;
    int*   bcount = (int*)(ws + off);    off += 512 * 4;
    int*   bstart = (int*)(ws + off);    off += 512 * 4;
    int*   gtail  = (int*)(ws + off);    off += 512 * 4;
    u16*   WbT    = (u16*)(ws + off);    off += 8192 * 2;
    u16*   xsb    = (u16*)(ws + off);    off += ((size_t)N * 64 * 2 + 255) & ~(size_t)255;
    unsigned* edgeBuf = (unsigned*)(ws + off); off += ((size_t)E * 4 + 255) & ~(size_t)255;

    float* mu = (float*)d_out;
    float* lv = mu + (size_t)N * 64;
    u16*   hb = (u16*)lv;                  // bf16 h, TILED inside lv slices

    const int B = 256;

    k_zero<<<(N + B - 1) / B, B, 0, stream>>>(deg, N);
    k_deg<<<(E + B - 1) / B, B, 0, stream>>>(dst, E, deg);
    k_dinv<<<(N + B - 1) / B, B, 0, stream>>>(deg, dinv, N);
    k_wbt<<<32, 256, 0, stream>>>(Wmu, Wlv, WbT);

    k_xs<<<(N * 16 + B - 1) / B, B, 0, stream>>>((const float4*)x, dinv, (ushort4*)xsb, N * 16);

    k_bktsum<<<NB, 256, 0, stream>>>(deg, bcount, N);
    k_bktscan<<<1, 512, 0, stream>>>(bcount, bstart, gtail, NB);
    k_split<<<256, 256, 0, stream>>>(src, dst, E, gtail, edgeBuf);

    k_aggb<<<NB, 1024, 0, stream>>>(xsb, dinv, bstart, bcount, edgeBuf, hb, N);

    k_gemm2<<<(N + 63) / 64, 256, 0, stream>>>(hb, WbT, bmu, blv, mu, lv, N);
}

// Round 10
// 183.068 us; speedup vs baseline: 3.6330x; 3.4903x over previous
//
#include <hip/hip_runtime.h>

// ---------------------------------------------------------------------------
// GCN variational encoder (mu, logvar) on MI355X — round 10.
//   h[n] = dinv[n] * ( xs[n] + sum_{s->n} xs[s] ),  xs = bf16(dinv*x)
//   mu = h@Wmu + bmu ; logvar = h@Wlv + blv   (MFMA, bf16 W^T)
// R10: R8/R9's per-edge wave-granular LDS-atomic aggregation was latency-
// poisoned (~520us, VGPR<=16, VALUBusy 3%) -> abandoned. Back to R7's PROVEN
// register-gather (8 subgroups x 8 lanes, 8 gathers in flight, shfl reduce),
// but the CSR is built PER BUCKET in LDS (histogram+scan+scatter of ~3070
// edges) from k_split's bucketed edge regions -> k_sort's 87us / 83MB random
// global scatter is gone.
// hb (bf16 h) stays TILED inside each block's own lv output slice.
// ---------------------------------------------------------------------------

typedef unsigned short u16;
typedef __attribute__((ext_vector_type(8))) short short8;   // 8 bf16 (4 VGPR)
typedef __attribute__((ext_vector_type(4))) float f32x4;

__device__ inline u16 f2bf(float f) {
    union { float f; unsigned u; } c; c.f = f;
    unsigned u = c.u;
    return (u16)((u + 0x7FFFu + ((u >> 16) & 1u)) >> 16);  // RNE
}
__device__ inline float bf2f(u16 h) {
    union { unsigned u; float f; } c; c.u = ((unsigned)h) << 16;
    return c.f;
}
__device__ inline float bfLo(unsigned u) {
    union { unsigned u; float f; } c; c.u = u << 16; return c.f;
}
__device__ inline float bfHi(unsigned u) {
    union { unsigned u; float f; } c; c.u = u & 0xFFFF0000u; return c.f;
}
__device__ inline unsigned packbf(float lo, float hi) {
    return ((unsigned)f2bf(hi) << 16) | (unsigned)f2bf(lo);
}

__global__ void k_zero(int* __restrict__ p, int n) {
    int i = blockIdx.x * blockDim.x + threadIdx.x;
    if (i < n) p[i] = 0;
}

__global__ void k_deg(const int* __restrict__ dst, int e, int* __restrict__ deg) {
    int i = blockIdx.x * blockDim.x + threadIdx.x;
    if (i < e) atomicAdd(&deg[dst[i]], 1);
}

__global__ void k_dinv(const int* __restrict__ deg, float* __restrict__ dinv, int n) {
    int i = blockIdx.x * blockDim.x + threadIdx.x;
    if (i < n) dinv[i] = rsqrtf((float)(deg[i] + 1));  // +1 = self loop
}

// xs = bf16(dinv[row] * x)
__global__ void k_xs(const float4* __restrict__ x4, const float* __restrict__ dinv,
                     ushort4* __restrict__ xs4, int n16) {
    int i = blockIdx.x * blockDim.x + threadIdx.x;
    if (i < n16) {
        float s = dinv[i >> 4];
        float4 v = x4[i];
        ushort4 o;
        o.x = f2bf(v.x * s); o.y = f2bf(v.y * s);
        o.z = f2bf(v.z * s); o.w = f2bf(v.w * s);
        xs4[i] = o;
    }
}

// WbT[mat][n][k] = bf16(W_mat[k][n])
__global__ void k_wbt(const float* __restrict__ Wmu, const float* __restrict__ Wlv,
                      u16* __restrict__ WbT) {
    int t = blockIdx.x * blockDim.x + threadIdx.x;
    if (t < 8192) {
        int mat = t >> 12;
        int n = (t >> 6) & 63;
        int k = t & 63;
        const float* W = mat ? Wlv : Wmu;
        WbT[t] = f2bf(W[k * 64 + n]);
    }
}

// bucket edge-count = sum of deg over the bucket's 256 nodes
__global__ __launch_bounds__(256) void k_bktsum(const int* __restrict__ deg,
                                                int* __restrict__ bcount, int n) {
    __shared__ int sm[256];
    const int node = (blockIdx.x << 8) + threadIdx.x;
    sm[threadIdx.x] = (node < n) ? deg[node] : 0;
    __syncthreads();
    for (int off = 128; off > 0; off >>= 1) {
        if (threadIdx.x < off) sm[threadIdx.x] += sm[threadIdx.x + off];
        __syncthreads();
    }
    if (threadIdx.x == 0) bcount[blockIdx.x] = sm[0];
}

// exclusive scan of bcount (nb <= 512) -> bstart, gtail
__global__ void k_bktscan(const int* __restrict__ bcount, int* __restrict__ bstart,
                          int* __restrict__ gtail, int nb) {
    __shared__ int sm[512];
    const int tid = threadIdx.x;
    int v = (tid < nb) ? bcount[tid] : 0;
    sm[tid] = v;
    __syncthreads();
    for (int off = 1; off < 512; off <<= 1) {
        int t = (tid >= off) ? sm[tid - off] : 0;
        __syncthreads();
        sm[tid] += t;
        __syncthreads();
    }
    if (tid < nb) { int s = sm[tid] - v; bstart[tid] = s; gtail[tid] = s; }
}

// --- multisplit: scatter edges into bucket regions (proven R8/R9) ----------
__global__ __launch_bounds__(256) void k_split(
        const int* __restrict__ src, const int* __restrict__ dst, int e,
        int* __restrict__ gtail, unsigned* __restrict__ edgeBuf) {
    __shared__ unsigned cnt[512];
    __shared__ unsigned base[512];
    const int tid = threadIdx.x;
    const int chunk = (e + gridDim.x - 1) / gridDim.x;
    const int e0 = blockIdx.x * chunk;
    const int e1 = min(e, e0 + chunk);

    for (int b = tid; b < 512; b += 256) cnt[b] = 0;
    __syncthreads();
    for (int i = e0 + tid; i < e1; i += 256)
        atomicAdd(&cnt[(unsigned)dst[i] >> 8], 1u);
    __syncthreads();
    for (int b = tid; b < 512; b += 256) {
        unsigned c = cnt[b];
        base[b] = c ? (unsigned)atomicAdd(&gtail[b], (int)c) : 0u;
        cnt[b] = 0;
    }
    __syncthreads();
    for (int i = e0 + tid; i < e1; i += 256) {
        const int d = dst[i];
        const int b = (unsigned)d >> 8;
        const unsigned p = base[b] + atomicAdd(&cnt[b], 1u);
        edgeBuf[p] = (unsigned)src[i] | ((unsigned)(d & 255) << 17);
    }
}

// --- bucket aggregation with LDS-local CSR + register gather ---------------
// One 512-thread block per 256-node bucket (~3070 edges, CAP=4608 = 18+sigma).
// Phase A: LDS histogram over 256 local nodes -> scan -> scatter packed
// edges into eloc[] (all in LDS).
// Phase B (R7-proven): one wave per node (8 rounds x 8 waves = wait, 32
// rounds x 8 waves = 256 nodes): 8 subgroups x 8 lanes; subgroup sub takes
// edges k=sub,sub+8,..: src from LDS, 16B/lane uint4 gather of the 128B
// bf16 xs row, register accumulate, 3x shfl_xor reduce, lanes 0-7 write
// the bf16 h row TILED inside the block's own lv slice.
#define CAP 4608
__global__ __launch_bounds__(512) void k_aggc(
        const u16* __restrict__ xs, const float* __restrict__ dinv,
        const int* __restrict__ bstart, const int* __restrict__ bcount,
        const unsigned* __restrict__ edgeBuf, u16* __restrict__ hb, int n) {
    __shared__ unsigned eloc[CAP];                 // 18 KB
    __shared__ int lcnt[256];
    __shared__ int lstart[256];
    __shared__ int lcur[256];
    const int tid = threadIdx.x;
    const int node0 = blockIdx.x << 8;

    for (int i = tid; i < 256; i += 512) lcnt[i] = 0;
    __syncthreads();

    const int e0  = bstart[blockIdx.x];
    const int cnt = min(bcount[blockIdx.x], CAP);

    // histogram over local dst
    for (int i = tid; i < cnt; i += 512)
        atomicAdd(&lcnt[edgeBuf[e0 + i] >> 17], 1);
    __syncthreads();

    // Hillis-Steele inclusive scan of lcnt into lstart, then make exclusive
    if (tid < 256) lstart[tid] = lcnt[tid];
    __syncthreads();
    for (int off = 1; off < 256; off <<= 1) {
        int v = 0;
        if (tid < 256 && tid >= off) v = lstart[tid - off];
        __syncthreads();
        if (tid < 256) lstart[tid] += v;
        __syncthreads();
    }
    if (tid < 256) {
        int ex = lstart[tid] - lcnt[tid];
        lstart[tid] = ex;
        lcur[tid] = ex;
    }
    __syncthreads();

    // scatter packed edges into local CSR order
    for (int i = tid; i < cnt; i += 512) {
        unsigned p = edgeBuf[e0 + i];
        int pos = atomicAdd(&lcur[p >> 17], 1);
        eloc[pos] = p;
    }
    __syncthreads();

    // register gather, one wave per node
    const int lane = tid & 63;
    const int w    = tid >> 6;        // 0..7
    const int sub  = lane >> 3;       // 0..7
    const int c8   = lane & 7;        // 16B chunk within the 128B row
    for (int r = w; r < 256; r += 8) {
        const int node = node0 + r;
        if (node >= n) continue;      // wave-uniform
        const int s0 = lstart[r];
        const int d  = lcnt[r];
        float a0=0.f,a1=0.f,a2=0.f,a3=0.f,a4=0.f,a5=0.f,a6=0.f,a7=0.f;
        for (int k = sub; k < d; k += 8) {
            const int s = eloc[s0 + k] & 0x1FFFF;   // uniform within subgroup
            uint4 v = *(const uint4*)(xs + (((size_t)s) << 6) + (c8 << 3));
            a0 += bfLo(v.x); a1 += bfHi(v.x);
            a2 += bfLo(v.y); a3 += bfHi(v.y);
            a4 += bfLo(v.z); a5 += bfHi(v.z);
            a6 += bfLo(v.w); a7 += bfHi(v.w);
        }
#define RED3(a) a += __shfl_xor(a, 8); a += __shfl_xor(a, 16); a += __shfl_xor(a, 32)
        RED3(a0); RED3(a1); RED3(a2); RED3(a3);
        RED3(a4); RED3(a5); RED3(a6); RED3(a7);
#undef RED3
        if (sub == 0) {
            uint4 v = *(const uint4*)(xs + (((size_t)node) << 6) + (c8 << 3));
            const float dn = dinv[node];
            float r0 = dn * (a0 + bfLo(v.x)), r1 = dn * (a1 + bfHi(v.x));
            float r2 = dn * (a2 + bfLo(v.y)), r3 = dn * (a3 + bfHi(v.y));
            float r4 = dn * (a4 + bfLo(v.z)), r5 = dn * (a5 + bfHi(v.z));
            float r6 = dn * (a6 + bfLo(v.w)), r7 = dn * (a7 + bfHi(v.w));
            uint4 o;
            o.x = packbf(r0, r1); o.y = packbf(r2, r3);
            o.z = packbf(r4, r5); o.w = packbf(r6, r7);
            *(uint4*)(hb + (size_t)(node >> 6) * 8192 + (size_t)(node & 63) * 64 + (c8 << 3)) = o;
        }
    }
}
#undef CAP

// --- MFMA dual GEMM (unchanged from R7) ------------------------------------
__global__ __launch_bounds__(256) void k_gemm2(
        const u16* __restrict__ hb, const u16* __restrict__ WbT,
        const float* __restrict__ bmu, const float* __restrict__ blv,
        float* __restrict__ mu, float* __restrict__ lv, int n) {
    const int tid  = threadIdx.x;
    const int lane = tid & 63;
    const int w    = tid >> 6;          // wave 0..3
    const int row0 = blockIdx.x * 64;
    const int m    = lane & 15;
    const int kg   = lane >> 4;         // 0..3

    const u16* hrow = hb + (size_t)blockIdx.x * 8192 + (size_t)(w * 16 + m) * 64 + kg * 8;
    short8 aF0 = *(const short8*)(hrow);
    short8 aF1 = *(const short8*)(hrow + 32);

    short8 bF[2][4][2];
    #pragma unroll
    for (int mat = 0; mat < 2; ++mat)
        #pragma unroll
        for (int ct = 0; ct < 4; ++ct)
            #pragma unroll
            for (int kh = 0; kh < 2; ++kh)
                bF[mat][ct][kh] = *(const short8*)(
                    WbT + mat * 4096 + (ct * 16 + m) * 64 + kh * 32 + kg * 8);

    __syncthreads();   // drain hb reads before any wave's lv stores

    #pragma unroll
    for (int mat = 0; mat < 2; ++mat) {
        const float* __restrict__ bias = mat ? blv : bmu;
        float* __restrict__ outp       = mat ? lv  : mu;
        #pragma unroll
        for (int ct = 0; ct < 4; ++ct) {
            const float bj = bias[ct * 16 + m];
            f32x4 acc = {bj, bj, bj, bj};
            acc = __builtin_amdgcn_mfma_f32_16x16x32_bf16(aF0, bF[mat][ct][0], acc, 0, 0, 0);
            acc = __builtin_amdgcn_mfma_f32_16x16x32_bf16(aF1, bF[mat][ct][1], acc, 0, 0, 0);
            #pragma unroll
            for (int i = 0; i < 4; ++i) {
                const int row = row0 + w * 16 + kg * 4 + i;
                if (row < n) outp[(size_t)row * 64 + ct * 16 + m] = acc[i];
            }
        }
    }
}

extern "C" void kernel_launch(void* const* d_in, const int* in_sizes, int n_in,
                              void* d_out, int out_size, void* d_ws, size_t ws_size,
                              hipStream_t stream) {
    const float* x   = (const float*)d_in[0];
    const int* eidx  = (const int*)d_in[1];
    const float* Wmu = (const float*)d_in[2];
    const float* bmu = (const float*)d_in[3];
    const float* Wlv = (const float*)d_in[4];
    const float* blv = (const float*)d_in[5];

    const int N = in_sizes[0] / 64;
    const int E = in_sizes[1] / 2;
    const int* src = eidx;
    const int* dst = eidx + E;
    const int NB = (N + 255) >> 8;        // 391 buckets of 256 nodes (<=512)

    // ws: deg dinv bcount bstart gtail WbT xs(bf16) edgeBuf  (~18.4 MB)
    char* ws = (char*)d_ws;
    size_t off = 0;
    int*   deg    = (int*)(ws + off);    off += ((size_t)N * 4 + 255) & ~(size_t)255;
    float* dinv   = (float*)(ws + off);  off += ((size_t)N * 4 + 255) & ~(size_t)255;
    int*   bcount = (int*)(ws + off);    off += 512 * 4;
    int*   bstart = (int*)(ws + off);    off += 512 * 4;
    int*   gtail  = (int*)(ws + off);    off += 512 * 4;
    u16*   WbT    = (u16*)(ws + off);    off += 8192 * 2;
    u16*   xsb    = (u16*)(ws + off);    off += ((size_t)N * 64 * 2 + 255) & ~(size_t)255;
    unsigned* edgeBuf = (unsigned*)(ws + off); off += ((size_t)E * 4 + 255) & ~(size_t)255;

    float* mu = (float*)d_out;
    float* lv = mu + (size_t)N * 64;
    u16*   hb = (u16*)lv;                  // bf16 h, TILED inside lv slices

    const int B = 256;

    k_zero<<<(N + B - 1) / B, B, 0, stream>>>(deg, N);
    k_deg<<<(E + B - 1) / B, B, 0, stream>>>(dst, E, deg);
    k_dinv<<<(N + B - 1) / B, B, 0, stream>>>(deg, dinv, N);
    k_wbt<<<32, 256, 0, stream>>>(Wmu, Wlv, WbT);

    k_xs<<<(N * 16 + B - 1) / B, B, 0, stream>>>((const float4*)x, dinv, (ushort4*)xsb, N * 16);

    k_bktsum<<<NB, 256, 0, stream>>>(deg, bcount, N);
    k_bktscan<<<1, 512, 0, stream>>>(bcount, bstart, gtail, NB);
    k_split<<<256, 256, 0, stream>>>(src, dst, E, gtail, edgeBuf);

    k_aggc<<<NB, 512, 0, stream>>>(xsb, dinv, bstart, bcount, edgeBuf, hb, N);

    k_gemm2<<<(N + 63) / 64, 256, 0, stream>>>(hb, WbT, bmu, blv, mu, lv, N);
}